// Round 13
// baseline (290.062 us; speedup 1.0000x reference)
//
#include <hip/hip_runtime.h>
#include <math.h>

// ---------------------------------------------------------------------------
// ASAP pooling block, fixed shapes.
// ---------------------------------------------------------------------------
constexpr int N_ = 20000;
constexpr int E_ = 320000;
constexpr int M_ = E_ + N_;      // edges incl. self loops
constexpr int F_ = 64;
constexpr int K_ = 256;
constexpr int TCAP = 32768;      // S-triplet capacity (expected ~4400)
constexpr int OUT_WORDS = K_ * F_ + K_ * K_ + K_;   // 82176

// ---- workspace layout (word offsets; 16B-aligned where float4-read) -------
constexpr size_t O_CSRC = 0;                           // CSR(by col) source node
constexpr size_t O_CNRM = O_CSRC + M_;                 // CSR gcn norm weight
constexpr size_t O_SC   = O_CNRM + M_;                 // CSR attention exp(score)
constexpr size_t O_BUFA = O_SC + M_;
constexpr size_t O_BUFB = O_BUFA + (size_t)N_ * F_;
constexpr size_t O_BUFC = O_BUFB + (size_t)N_ * F_;
constexpr size_t O_CPTR = O_BUFC + (size_t)N_ * F_;    // N+1 (padded to N+4)
constexpr size_t O_Q2   = O_CPTR + N_ + 4;
constexpr size_t O_DEN  = O_Q2 + N_;
constexpr size_t O_AV   = O_DEN + N_;
constexpr size_t O_BV   = O_AV + N_;
constexpr size_t O_C3   = O_BV + N_;
constexpr size_t O_FIT  = O_C3 + N_;
constexpr size_t O_TPTR = O_FIT + N_;                  // N+1 (padded to N+4)
constexpr size_t O_TI   = O_TPTR + N_ + 4;
constexpr size_t O_TK   = O_TI + TCAP;
constexpr size_t O_TV   = O_TK + TCAP;
constexpr size_t O_TIDX = O_TV + TCAP;
constexpr size_t O_PERM = O_TIDX + TCAP;               // 256 (uint)
constexpr size_t O_FITS = O_PERM + K_;                 // 256 (f32)
constexpr size_t O_WQ   = O_FITS + K_;                 // 65 (lin/att folded vec + bias)
// zero-initialized region:
constexpr size_t O_ZR   = O_WQ + 72;
constexpr size_t O_CNT  = O_ZR;                        // N (in-degree counts)
constexpr size_t O_CUR  = O_CNT + N_;                  // N
constexpr size_t O_TCNT = O_CUR + N_;                  // N
constexpr size_t O_TCUR = O_TCNT + N_;                 // N
constexpr size_t O_CTRL = O_TCUR + N_;                 // 8 (ctrl[5]=trip count)
constexpr size_t ZR_WORDS = O_CTRL + 8 - O_ZR;

__device__ __forceinline__ float4 ld4(const float* p) { return *reinterpret_cast<const float4*>(p); }
__device__ __forceinline__ void st4(float* p, float4 v) { *reinterpret_cast<float4*>(p) = v; }

// ---------------------------------------------------------------------------
__global__ void init_k(unsigned* __restrict__ zr, float* __restrict__ dout) {
  int g = blockIdx.x * blockDim.x + threadIdx.x;
  if (g < (int)ZR_WORDS) zr[g] = 0u;
  if (g < OUT_WORDS) dout[g] = 0.0f;
}

// degree counts; last block also computes wq = linW@attW[:64], wq[64]=linb·attW
__global__ void build_edges_k(const int* __restrict__ ei, unsigned* __restrict__ cnt,
                              const float* __restrict__ linW, const float* __restrict__ linb,
                              const float* __restrict__ attW, float* __restrict__ wq) {
  if (blockIdx.x == gridDim.x - 1) {
    int f = threadIdx.x;
    if (f < 64) {
      float s = 0.0f;
      for (int c = 0; c < 64; ++c) s += linW[f * 64 + c] * attW[c];
      wq[f] = s;
      float b = linb[f] * attW[f];
      for (int off = 32; off; off >>= 1) b += __shfl_down(b, off);
      if (f == 0) wq[64] = b;
    }
    return;
  }
  int g = blockIdx.x * blockDim.x + threadIdx.x;
  if (g >= M_) return;
  int c = (g < E_) ? ei[E_ + g] : g - E_;
  atomicAdd(&cnt[c], 1u);
}

// single-block exclusive prefix (n bins -> ptr[n+1]); LDS-staged, 4 barriers
__global__ __launch_bounds__(1024) void prefix_k(const unsigned* __restrict__ cnt,
                                                 unsigned* __restrict__ ptr, int n) {
  __shared__ unsigned buf[N_];
  __shared__ unsigned wsum[16];
  __shared__ unsigned s_total;
  int t = threadIdx.x;
  int wv = t >> 6, ln = t & 63;
  for (int i = t; i < n; i += 1024) buf[i] = cnt[i];
  __syncthreads();
  int chunk = (n + 1023) >> 10;
  int i0 = t * chunk;
  unsigned s = 0;
  for (int j = 0; j < chunk; ++j) { int i = i0 + j; if (i < n) s += buf[i]; }
  unsigned pre = s;
  for (int off = 1; off < 64; off <<= 1) {
    unsigned v = __shfl_up(pre, off);
    if (ln >= off) pre += v;
  }
  if (ln == 63) wsum[wv] = pre;
  __syncthreads();
  if (t == 0) {
    unsigned run = 0;
    for (int w = 0; w < 16; ++w) { unsigned v = wsum[w]; wsum[w] = run; run += v; }
    s_total = run;
  }
  __syncthreads();
  unsigned run = wsum[wv] + (pre - s);   // exclusive prefix at chunk start
  for (int j = 0; j < chunk; ++j) {
    int i = i0 + j;
    if (i < n) { unsigned v = buf[i]; buf[i] = run; run += v; }
  }
  __syncthreads();
  for (int i = t; i < n; i += 1024) ptr[i] = buf[i];
  if (t == 0) ptr[n] = s_total;
}

// scatter edge -> CSR(by col) position; store src node and gcn norm weight
__global__ void scatter_csr_k(const int* __restrict__ ei,
                              const unsigned* __restrict__ cptr, unsigned* __restrict__ cur,
                              int* __restrict__ csrc, float* __restrict__ cnrm) {
  int g = blockIdx.x * blockDim.x + threadIdx.x;
  if (g >= M_) return;
  int r, c;
  if (g < E_) { r = ei[g]; c = ei[E_ + g]; } else { r = g - E_; c = r; }
  unsigned pos = cptr[c] + atomicAdd(&cur[c], 1u);
  csrc[pos] = r;
  float dr = (float)(cptr[r + 1] - cptr[r]);
  float dc = (float)(cptr[c + 1] - cptr[c]);
  cnrm[pos] = (1.0f / sqrtf(dr)) * (1.0f / sqrtf(dc));
}

// Y[n,64] = X[n,64] @ W[64,64]. Tiled: 64 rows/block, 256 threads.
__global__ void gemm64_k(const float* __restrict__ X, const float* __restrict__ W,
                         float* __restrict__ Y) {
  __shared__ float xs[64][64];
  __shared__ float wsh[64][64];
  int t = threadIdx.x;
  int r0 = blockIdx.x * 64;
  for (int i = 0; i < 16; ++i) {
    int idx = t + i * 256;
    wsh[idx >> 6][idx & 63] = W[idx];
  }
  for (int i = 0; i < 16; ++i) {
    int idx = t + i * 256;
    int r = idx >> 6, c = idx & 63;
    xs[r][c] = (r0 + r < N_) ? X[(size_t)(r0 + r) * F_ + c] : 0.0f;
  }
  __syncthreads();
  int c = t & 63, rg = t >> 6;
  float acc[16];
#pragma unroll
  for (int m = 0; m < 16; ++m) acc[m] = 0.0f;
  for (int k = 0; k < 64; ++k) {
    float w = wsh[k][c];
#pragma unroll
    for (int m = 0; m < 16; ++m) acc[m] += xs[rg + 4 * m][k] * w;
  }
  for (int m = 0; m < 16; ++m) {
    int r = r0 + rg + 4 * m;
    if (r < N_) Y[(size_t)r * F_ + c] = acc[m];
  }
}

// GCN aggregate: wave per node; edge indices/weights coalesced into registers,
// broadcast via shfl; 16 lanes x float4 per row, 4 edges in flight.
// EPI 1: q2[i] = relu_out · attW[64:128].
template<int EPI>
__global__ void agg_gcn_k(const float* __restrict__ H, const int* __restrict__ csrc,
                          const float* __restrict__ wts, const unsigned* __restrict__ cptr,
                          const float* __restrict__ bias, float* __restrict__ Y,
                          const float* __restrict__ attW, float* __restrict__ q2) {
  int wid = blockIdx.x * (blockDim.x >> 6) + (threadIdx.x >> 6);
  int lane = threadIdx.x & 63;
  if (wid >= N_) return;
  int sub = lane >> 4, fq = lane & 15;
  unsigned p0 = cptr[wid], p1 = cptr[wid + 1];
  float ax = 0.f, ay = 0.f, az = 0.f, aw = 0.f;
  for (unsigned base = p0; base < p1; base += 64) {
    int cnt = (int)min(64u, p1 - base);
    int myS = (lane < cnt) ? csrc[base + lane] : 0;
    float myW = (lane < cnt) ? wts[base + lane] : 0.0f;
    for (int e = 0; e < cnt; e += 4) {
      int idx = e + sub;
      int s_e = __shfl(myS, idx);
      float w_e = __shfl(myW, idx);
      if (idx < cnt) {
        float4 h = ld4(H + ((size_t)s_e << 6) + 4 * fq);
        ax += w_e * h.x; ay += w_e * h.y; az += w_e * h.z; aw += w_e * h.w;
      }
    }
  }
#pragma unroll
  for (int off = 16; off <= 32; off <<= 1) {
    ax += __shfl_xor(ax, off); ay += __shfl_xor(ay, off);
    az += __shfl_xor(az, off); aw += __shfl_xor(aw, off);
  }
  float4 b4 = ld4(bias + 4 * fq);
  ax = fmaxf(ax + b4.x, 0.f); ay = fmaxf(ay + b4.y, 0.f);
  az = fmaxf(az + b4.z, 0.f); aw = fmaxf(aw + b4.w, 0.f);
  if (sub == 0) { float4 o{ax, ay, az, aw}; st4(Y + ((size_t)wid << 6) + 4 * fq, o); }
  if (EPI == 1) {
    float4 a4 = ld4(attW + 64 + 4 * fq);
    float v = ax * a4.x + ay * a4.y + az * a4.z + aw * a4.w;
#pragma unroll
    for (int off = 1; off <= 8; off <<= 1) v += __shfl_xor(v, off);
    if (lane == 0) q2[wid] = v;
  }
}

// Fused attention: segment-max (+folded lin·att -> q1) -> leaky/softmax stats
// -> xc weighted gather (+le1/le2/le3 dots). Wave per node.
// Fast path deg<=64: edge ids + e-values live in registers across phases.
__global__ void attn_fused_k(const float* __restrict__ X2, const int* __restrict__ csrc,
                             const unsigned* __restrict__ cptr, const float* __restrict__ q2,
                             const float* __restrict__ attb, const float* __restrict__ wq,
                             float* __restrict__ sc, float* __restrict__ den,
                             float* __restrict__ XC,
                             const float* __restrict__ le1W, const float* __restrict__ le1b,
                             const float* __restrict__ le2W, const float* __restrict__ le3W,
                             const float* __restrict__ le3b, float* __restrict__ av,
                             float* __restrict__ bv, float* __restrict__ c3) {
  int wid = blockIdx.x * (blockDim.x >> 6) + (threadIdx.x >> 6);
  int lane = threadIdx.x & 63;
  if (wid >= N_) return;
  int sub = lane >> 4, fq = lane & 15;
  unsigned p0 = cptr[wid], p1 = cptr[wid + 1];
  int deg = (int)(p1 - p0);
  float ax = 0.f, ay = 0.f, az = 0.f, aw = 0.f;   // phase-C accumulator
  float d;                                         // softmax denom

  if (deg <= 64) {
    int myS = (lane < deg) ? csrc[p0 + lane] : 0;
    // phase A: feature-wise segment max (4 edges in flight)
    float mx = -INFINITY, my = -INFINITY, mz = -INFINITY, mw = -INFINITY;
    for (int e = 0; e < deg; e += 4) {
      int idx = e + sub;
      int s_e = __shfl(myS, idx);
      if (idx < deg) {
        float4 h = ld4(X2 + ((size_t)s_e << 6) + 4 * fq);
        mx = fmaxf(mx, h.x); my = fmaxf(my, h.y); mz = fmaxf(mz, h.z); mw = fmaxf(mw, h.w);
      }
    }
#pragma unroll
    for (int off = 16; off <= 32; off <<= 1) {
      mx = fmaxf(mx, __shfl_xor(mx, off)); my = fmaxf(my, __shfl_xor(my, off));
      mz = fmaxf(mz, __shfl_xor(mz, off)); mw = fmaxf(mw, __shfl_xor(mw, off));
    }
    float4 w4 = ld4(wq + 4 * fq);
    float q1v = mx * w4.x + my * w4.y + mz * w4.z + mw * w4.w;
#pragma unroll
    for (int off = 1; off <= 8; off <<= 1) q1v += __shfl_xor(q1v, off);
    float base = q1v + wq[64] + attb[0];
    // phase B: per-lane edge score -> max -> e -> denom (e stays in reg)
    float sv = -INFINITY;
    if (lane < deg) {
      float s = base + q2[myS];
      sv = (s > 0.0f) ? s : 0.2f * s;
    }
    float m = sv;
#pragma unroll
    for (int off = 1; off <= 32; off <<= 1) m = fmaxf(m, __shfl_xor(m, off));
    float e_l = (lane < deg) ? expf(sv - m) : 0.0f;
    d = e_l;
#pragma unroll
    for (int off = 1; off <= 32; off <<= 1) d += __shfl_xor(d, off);
    if (lane < deg) sc[p0 + lane] = e_l;      // coalesced store
    if (lane == 0) den[wid] = d;
    // phase C: weighted gather; weights broadcast from registers
    for (int e = 0; e < deg; e += 4) {
      int idx = e + sub;
      int s_e = __shfl(myS, idx);
      float w_e = __shfl(e_l, idx);
      if (idx < deg) {
        float4 h = ld4(X2 + ((size_t)s_e << 6) + 4 * fq);
        ax += w_e * h.x; ay += w_e * h.y; az += w_e * h.z; aw += w_e * h.w;
      }
    }
  } else {
    // slow general path (deg > 64): chunked, sc round-trips through memory
    float mx = -INFINITY, my = -INFINITY, mz = -INFINITY, mw = -INFINITY;
    for (unsigned p = p0 + sub; p < p1; p += 4) {
      int s = csrc[p];
      float4 h = ld4(X2 + ((size_t)s << 6) + 4 * fq);
      mx = fmaxf(mx, h.x); my = fmaxf(my, h.y); mz = fmaxf(mz, h.z); mw = fmaxf(mw, h.w);
    }
#pragma unroll
    for (int off = 16; off <= 32; off <<= 1) {
      mx = fmaxf(mx, __shfl_xor(mx, off)); my = fmaxf(my, __shfl_xor(my, off));
      mz = fmaxf(mz, __shfl_xor(mz, off)); mw = fmaxf(mw, __shfl_xor(mw, off));
    }
    float4 w4 = ld4(wq + 4 * fq);
    float q1v = mx * w4.x + my * w4.y + mz * w4.z + mw * w4.w;
#pragma unroll
    for (int off = 1; off <= 8; off <<= 1) q1v += __shfl_xor(q1v, off);
    float base = q1v + wq[64] + attb[0];
    float m = -INFINITY;
    for (unsigned p = p0 + lane; p < p1; p += 64) {
      float s = base + q2[csrc[p]];
      s = (s > 0.0f) ? s : 0.2f * s;
      m = fmaxf(m, s);
    }
#pragma unroll
    for (int off = 1; off <= 32; off <<= 1) m = fmaxf(m, __shfl_xor(m, off));
    d = 0.0f;
    for (unsigned p = p0 + lane; p < p1; p += 64) {
      float s = base + q2[csrc[p]];
      s = (s > 0.0f) ? s : 0.2f * s;
      float e = expf(s - m);
      sc[p] = e;
      d += e;
    }
#pragma unroll
    for (int off = 1; off <= 32; off <<= 1) d += __shfl_xor(d, off);
    if (lane == 0) den[wid] = d;
    for (unsigned p = p0 + sub; p < p1; p += 4) {
      int s = csrc[p];
      float w = sc[p];     // broadcast load (written above)
      float4 h = ld4(X2 + ((size_t)s << 6) + 4 * fq);
      ax += w * h.x; ay += w * h.y; az += w * h.z; aw += w * h.w;
    }
  }
#pragma unroll
  for (int off = 16; off <= 32; off <<= 1) {
    ax += __shfl_xor(ax, off); ay += __shfl_xor(ay, off);
    az += __shfl_xor(az, off); aw += __shfl_xor(aw, off);
  }
  float inv = 1.0f / d;
  ax *= inv; ay *= inv; az *= inv; aw *= inv;
  if (sub == 0) { float4 o{ax, ay, az, aw}; st4(XC + ((size_t)wid << 6) + 4 * fq, o); }
  float4 l1 = ld4(le1W + 4 * fq), l2 = ld4(le2W + 4 * fq), l3 = ld4(le3W + 4 * fq);
  float s1 = ax * l1.x + ay * l1.y + az * l1.z + aw * l1.w;
  float s2 = ax * l2.x + ay * l2.y + az * l2.z + aw * l2.w;
  float s3 = ax * l3.x + ay * l3.y + az * l3.z + aw * l3.w;
#pragma unroll
  for (int off = 1; off <= 8; off <<= 1) {
    s1 += __shfl_xor(s1, off); s2 += __shfl_xor(s2, off); s3 += __shfl_xor(s3, off);
  }
  if (lane == 0) { av[wid] = s1 + le1b[0]; bv[wid] = s2; c3[wid] = s3 + le3b[0]; }
}

// fitness: wave per node, lanes split edges
__global__ void fitness_k(const unsigned* __restrict__ cptr, const int* __restrict__ csrc,
                          const float* __restrict__ av, const float* __restrict__ bv,
                          const float* __restrict__ c3, float* __restrict__ fit) {
  int wid = blockIdx.x * (blockDim.x >> 6) + (threadIdx.x >> 6);
  int lane = threadIdx.x & 63;
  if (wid >= N_) return;
  unsigned p0 = cptr[wid], p1 = cptr[wid + 1];
  float s = 0.0f;
  for (unsigned p = p0 + lane; p < p1; p += 64) s += av[csrc[p]];
#pragma unroll
  for (int off = 1; off <= 32; off <<= 1) s += __shfl_xor(s, off);
  if (lane == 0) {
    float deg = (float)(p1 - p0);
    float val = s - deg * bv[wid] + c3[wid];
    fit[wid] = 1.0f / (1.0f + expf(-val));
  }
}

// ---------------------------------------------------------------------------
// Single-block exact top-K v3: fit bits staged in LDS; 4x8-bit radix select
// (fit>0 so bit order == value order); single-wave shfl scans; exact
// smallest-index tie-break; rank-sort of the 256 winners. ~25 barriers total.
// ---------------------------------------------------------------------------
__global__ __launch_bounds__(1024) void topk_k(const float* __restrict__ fit,
                                               unsigned* __restrict__ perm_i,
                                               float* __restrict__ fit_s,
                                               float* __restrict__ out_perm) {
  __shared__ unsigned fb_s[N_];          // 80000 B (gfx950: 160 KiB LDS/CU)
  __shared__ unsigned hist[256 * 16];    // 16384 B
  __shared__ unsigned scn[256];
  __shared__ unsigned long long keys[K_];
  __shared__ unsigned rnk[K_];
  __shared__ unsigned s_pfx, s_rem, s_cnt, s_bstar, s_rem2, s_cut, s_all;
  int t = threadIdx.x;
  int sub = t & 15;
  int wv = t >> 6, ln = t & 63;

  for (int i = t; i < N_; i += 1024) fb_s[i] = __float_as_uint(fit[i]);
  if (t == 0) { s_cnt = 0; s_all = 0; }
  if (t < K_) rnk[t] = 0;
  __syncthreads();

  unsigned msk = 0, pfx = 0, rem = K_;
  for (int lvl = 0; lvl < 4; ++lvl) {
    const int shift = 24 - lvl * 8;
    for (int i = t; i < 256 * 16; i += 1024) hist[i] = 0;
    __syncthreads();
    for (int i = t; i < N_; i += 1024) {
      unsigned fb = fb_s[i];
      if ((fb & msk) == pfx)
        atomicAdd(&hist[(((fb >> shift) & 0xFF) << 4) + sub], 1u);
    }
    __syncthreads();
    if (t < 256) {
      unsigned h = 0;
#pragma unroll
      for (int s = 0; s < 16; ++s) h += hist[(t << 4) + s];
      scn[t] = h;
    }
    __syncthreads();
    if (wv == 0) {  // suffix-scan 256 bins in one wave (4 bins/lane)
      unsigned b0 = scn[4 * ln], b1 = scn[4 * ln + 1], b2 = scn[4 * ln + 2], b3 = scn[4 * ln + 3];
      unsigned loc = b0 + b1 + b2 + b3;
      unsigned suf = loc;
      for (int off = 1; off < 64; off <<= 1) {
        unsigned v = __shfl_down(suf, off);
        if (ln + off < 64) suf += v;
      }
      unsigned above = suf - loc;          // sum of bins > 4ln+3
      unsigned s3 = above + b3;
      unsigned s2 = s3 + b2;
      unsigned s1 = s2 + b1;
      unsigned s0 = s1 + b0;
      if (s0 >= rem && s1 < rem)    { s_pfx = pfx | ((unsigned)(4 * ln)     << shift); s_rem = rem - s1; }
      if (s1 >= rem && s2 < rem)    { s_pfx = pfx | ((unsigned)(4 * ln + 1) << shift); s_rem = rem - s2; }
      if (s2 >= rem && s3 < rem)    { s_pfx = pfx | ((unsigned)(4 * ln + 2) << shift); s_rem = rem - s3; }
      if (s3 >= rem && above < rem) { s_pfx = pfx | ((unsigned)(4 * ln + 3) << shift); s_rem = rem - above; }
    }
    __syncthreads();
    pfx = s_pfx; rem = s_rem; msk |= (0xFFu << shift);
  }
  // pfx = exact bits of K-th largest; rem = #ties to take (smallest indices).
  for (int i = t; i < 256 * 16; i += 1024) hist[i] = 0;
  __syncthreads();
  // fused: emit strict winners + histogram ties by idx>>7 (157 bins)
  for (int i = t; i < N_; i += 1024) {
    unsigned fb = fb_s[i];
    if (fb > pfx) {
      unsigned j = atomicAdd(&s_cnt, 1u);
      keys[j] = ((unsigned long long)fb << 32) | (unsigned long long)(0xFFFFFFFFu - (unsigned)i);
    } else if (fb == pfx) {
      atomicAdd(&hist[((i >> 7) << 4) + sub], 1u);
    }
  }
  __syncthreads();
  if (t < 256) {
    unsigned h = 0;
#pragma unroll
    for (int s = 0; s < 16; ++s) h += hist[(t << 4) + s];
    scn[t] = h;
  }
  __syncthreads();
  if (wv == 0) {  // prefix-scan 256 bins in one wave
    unsigned b0 = scn[4 * ln], b1 = scn[4 * ln + 1], b2 = scn[4 * ln + 2], b3 = scn[4 * ln + 3];
    unsigned loc = b0 + b1 + b2 + b3;
    unsigned pre = loc;
    for (int off = 1; off < 64; off <<= 1) {
      unsigned v = __shfl_up(pre, off);
      if (ln >= off) pre += v;
    }
    unsigned below = pre - loc;
    unsigned p0 = below + b0;
    unsigned p1 = p0 + b1;
    unsigned p2 = p1 + b2;
    unsigned p3 = p2 + b3;
    if (ln == 63 && p3 == rem) s_all = 1u;   // all ties taken
    if (p0 >= rem && below < rem) { s_bstar = 4u * ln;     s_rem2 = rem - below; }
    if (p1 >= rem && p0 < rem)    { s_bstar = 4u * ln + 1; s_rem2 = rem - p0; }
    if (p2 >= rem && p1 < rem)    { s_bstar = 4u * ln + 2; s_rem2 = rem - p1; }
    if (p3 >= rem && p2 < rem)    { s_bstar = 4u * ln + 3; s_rem2 = rem - p2; }
  }
  __syncthreads();
  unsigned bstar = s_bstar, rem2 = s_rem2;
  if (s_all) {
    for (int i = t; i < N_; i += 1024)
      if (fb_s[i] == pfx) {
        unsigned j = atomicAdd(&s_cnt, 1u);
        keys[j] = ((unsigned long long)pfx << 32) | (unsigned long long)(0xFFFFFFFFu - (unsigned)i);
      }
  } else {
    // tie level B: bins = idx & 127 within bstar (unique -> h in {0,1})
    for (int i = t; i < 256 * 16; i += 1024) hist[i] = 0;
    __syncthreads();
    for (int i = t; i < N_; i += 1024)
      if (fb_s[i] == pfx && (unsigned)(i >> 7) == bstar)
        atomicAdd(&hist[((i & 127) << 4) + sub], 1u);
    __syncthreads();
    if (t < 128) {
      unsigned h = 0;
#pragma unroll
      for (int s = 0; s < 16; ++s) h += hist[(t << 4) + s];
      scn[t] = h;
    }
    __syncthreads();
    if (wv == 0) {  // prefix-scan 128 bins (2/lane)
      unsigned b0 = scn[2 * ln], b1 = scn[2 * ln + 1];
      unsigned loc = b0 + b1;
      unsigned pre = loc;
      for (int off = 1; off < 64; off <<= 1) {
        unsigned v = __shfl_up(pre, off);
        if (ln >= off) pre += v;
      }
      unsigned below = pre - loc;
      unsigned p0 = below + b0;
      unsigned p1 = p0 + b1;
      if (p0 >= rem2 && below < rem2) s_cut = 2u * ln;
      if (p1 >= rem2 && p0 < rem2)    s_cut = 2u * ln + 1;
    }
    __syncthreads();
    unsigned cut = s_cut;
    for (int i = t; i < N_; i += 1024) {
      if (fb_s[i] == pfx) {
        unsigned hi = (unsigned)(i >> 7), lo = (unsigned)(i & 127);
        if (hi < bstar || (hi == bstar && lo <= cut)) {
          unsigned j = atomicAdd(&s_cnt, 1u);
          keys[j] = ((unsigned long long)pfx << 32) | (unsigned long long)(0xFFFFFFFFu - (unsigned)i);
        }
      }
    }
  }
  __syncthreads();
  // rank sort: 1024 threads, key t&255, segment t>>8 (64 comparisons each)
  {
    int k = t & 255, seg = t >> 8;
    unsigned long long my = keys[k];
    unsigned r = 0;
    for (int j = seg * 64; j < seg * 64 + 64; ++j) r += (keys[j] > my) ? 1u : 0u;
    if (r) atomicAdd(&rnk[k], r);
  }
  __syncthreads();
  if (t < K_) {
    unsigned long long kk = keys[t];
    unsigned r = rnk[t];
    unsigned idx = 0xFFFFFFFFu - (unsigned)(kk & 0xFFFFFFFFu);
    perm_i[r] = idx;
    fit_s[r] = __uint_as_float((unsigned)(kk >> 32));
    out_perm[r] = (float)idx;
  }
}

__global__ void xnew_k(const float* __restrict__ XC, const unsigned* __restrict__ perm_i,
                       const float* __restrict__ fit_s, float* __restrict__ out) {
  int g = blockIdx.x * blockDim.x + threadIdx.x;
  if (g >= K_ * F_ / 4) return;
  int k = g >> 4, fq = g & 15;
  float4 v = ld4(XC + ((size_t)perm_i[k] << 6) + 4 * fq);
  float f = fit_s[k];
  v.x *= f; v.y *= f; v.z *= f; v.w *= f;
  st4(out + ((size_t)k << 6) + 4 * fq, v);
}

// build S triplets directly from the 256 selected nodes' CSR ranges
__global__ void trip_sel_k(const unsigned* __restrict__ perm_i, const unsigned* __restrict__ cptr,
                           const int* __restrict__ csrc, const float* __restrict__ sc,
                           const float* __restrict__ den,
                           int* __restrict__ ti, int* __restrict__ tk, float* __restrict__ tv,
                           unsigned* __restrict__ tcnt, unsigned* __restrict__ ctrl) {
  int k = blockIdx.x * blockDim.x + threadIdx.x;
  if (k >= K_) return;
  unsigned i = perm_i[k];
  unsigned p0 = cptr[i], p1 = cptr[i + 1];
  float d = den[i];
  for (unsigned p = p0; p < p1; ++p) {
    unsigned j = atomicAdd(&ctrl[5], 1u);
    if (j < (unsigned)TCAP) {
      int r = csrc[p];
      ti[j] = r; tk[j] = k; tv[j] = sc[p] / d;
      atomicAdd(&tcnt[r], 1u);
    }
  }
}

__global__ void trip_scatter_k(const int* __restrict__ ti, const unsigned* __restrict__ tptr,
                               unsigned* __restrict__ tcur, unsigned* __restrict__ tidx,
                               const unsigned* __restrict__ ctrl) {
  int g = blockIdx.x * blockDim.x + threadIdx.x;
  unsigned cnt = ctrl[5]; if (cnt > (unsigned)TCAP) cnt = TCAP;
  if (g >= (int)cnt) return;
  int i = ti[g];
  unsigned pos = tptr[i] + atomicAdd(&tcur[i], 1u);
  tidx[pos] = (unsigned)g;
}

// A[k1,k2] += sum over edges of S[row,k1]*S[col,k2]
__global__ void anew_k(const int* __restrict__ ei,
                       const unsigned* __restrict__ tptr, const unsigned* __restrict__ tidx,
                       const int* __restrict__ tk, const float* __restrict__ tv,
                       float* __restrict__ A) {
  int g = blockIdx.x * blockDim.x + threadIdx.x;
  if (g >= M_) return;
  int i, j;
  if (g < E_) { i = ei[g]; j = ei[E_ + g]; } else { i = j = g - E_; }
  unsigned a0 = tptr[i], a1 = tptr[i + 1];
  if (a0 == a1) return;
  unsigned b0 = tptr[j], b1 = tptr[j + 1];
  if (b0 == b1) return;
  for (unsigned pa = a0; pa < a1; ++pa) {
    unsigned ta = tidx[pa];
    int k1 = tk[ta];
    float va = tv[ta];
    float* Arow = A + (size_t)k1 * K_;
    for (unsigned pb = b0; pb < b1; ++pb) {
      unsigned tb = tidx[pb];
      atomicAdd(&Arow[tk[tb]], va * tv[tb]);
    }
  }
}

__global__ void adiag_k(float* __restrict__ A) {
  int t = threadIdx.x;
  if (t < K_) A[(size_t)t * K_ + t] = 1.0f;
}

// ---------------------------------------------------------------------------
extern "C" void kernel_launch(void* const* d_in, const int* in_sizes, int n_in,
                              void* d_out, int out_size, void* d_ws, size_t ws_size,
                              hipStream_t stream) {
  const float* x     = (const float*)d_in[0];
  const int*   ei    = (const int*)d_in[1];
  const float* W0    = (const float*)d_in[2];
  const float* b0    = (const float*)d_in[3];
  const float* W1    = (const float*)d_in[4];
  const float* b1    = (const float*)d_in[5];
  const float* linW  = (const float*)d_in[6];
  const float* linb  = (const float*)d_in[7];
  const float* attW  = (const float*)d_in[8];
  const float* attb  = (const float*)d_in[9];
  const float* le1W  = (const float*)d_in[10];
  const float* le1b  = (const float*)d_in[11];
  const float* le2W  = (const float*)d_in[12];
  const float* le3W  = (const float*)d_in[13];
  const float* le3b  = (const float*)d_in[14];

  float*    wf = (float*)d_ws;
  unsigned* wu = (unsigned*)d_ws;
  int*      wi = (int*)d_ws;
  float*    out = (float*)d_out;

  int*      csrc  = wi + O_CSRC;
  float*    cnrm  = wf + O_CNRM;
  float*    sc    = wf + O_SC;
  float*    bufA  = wf + O_BUFA;
  float*    bufB  = wf + O_BUFB;
  float*    bufC  = wf + O_BUFC;
  unsigned* cptr  = wu + O_CPTR;
  float*    q2    = wf + O_Q2;
  float*    den   = wf + O_DEN;
  float*    av    = wf + O_AV;
  float*    bv    = wf + O_BV;
  float*    c3    = wf + O_C3;
  float*    fit   = wf + O_FIT;
  unsigned* tptr  = wu + O_TPTR;
  int*      ti    = wi + O_TI;
  int*      tk    = wi + O_TK;
  float*    tv    = wf + O_TV;
  unsigned* tidx  = wu + O_TIDX;
  unsigned* perm_i= wu + O_PERM;
  float*    fit_s = wf + O_FITS;
  float*    wq    = wf + O_WQ;
  unsigned* zr    = wu + O_ZR;
  unsigned* cnt   = wu + O_CNT;
  unsigned* cur   = wu + O_CUR;
  unsigned* tcnt  = wu + O_TCNT;
  unsigned* tcur  = wu + O_TCUR;
  unsigned* ctrl  = wu + O_CTRL;

  const int TB = 256;
  const int gM = (M_ + TB - 1) / TB;          // 1329
  const int gW = (N_ + 3) / 4;                // 5000 (wave-per-node, 4 waves/block)
  const int gG = (N_ + 63) / 64;              // 313 (gemm tiles)
  const int gZ = ((int)(ZR_WORDS > OUT_WORDS ? ZR_WORDS : OUT_WORDS) + TB - 1) / TB;

  hipLaunchKernelGGL(init_k, dim3(gZ), dim3(TB), 0, stream, zr, out);
  hipLaunchKernelGGL(build_edges_k, dim3(gM + 1), dim3(TB), 0, stream, ei, cnt,
                     linW, linb, attW, wq);
  hipLaunchKernelGGL(prefix_k, dim3(1), dim3(1024), 0, stream, cnt, cptr, N_);
  hipLaunchKernelGGL(scatter_csr_k, dim3(gM), dim3(TB), 0, stream, ei, cptr, cur, csrc, cnrm);

  // GCN layer 1: bufA = x@W0 ; bufB = relu(agg + b0)
  hipLaunchKernelGGL(gemm64_k, dim3(gG), dim3(TB), 0, stream, x, W0, bufA);
  hipLaunchKernelGGL((agg_gcn_k<0>), dim3(gW), dim3(TB), 0, stream, bufA, csrc, cnrm, cptr, b0, bufB,
                     nullptr, nullptr);
  // GCN layer 2: bufA = bufB@W1 ; bufC = relu(agg + b1) = x2 ; q2 epilogue
  hipLaunchKernelGGL(gemm64_k, dim3(gG), dim3(TB), 0, stream, bufB, W1, bufA);
  hipLaunchKernelGGL((agg_gcn_k<1>), dim3(gW), dim3(TB), 0, stream, bufA, csrc, cnrm, cptr, b1, bufC,
                     attW, q2);

  // fused attention pooling (xc -> bufB) + le dots
  hipLaunchKernelGGL(attn_fused_k, dim3(gW), dim3(TB), 0, stream, bufC, csrc, cptr, q2, attb, wq,
                     sc, den, bufB, le1W, le1b, le2W, le3W, le3b, av, bv, c3);

  // fitness + exact top-K
  hipLaunchKernelGGL(fitness_k, dim3(gW), dim3(TB), 0, stream, cptr, csrc, av, bv, c3, fit);
  hipLaunchKernelGGL(topk_k, dim3(1), dim3(1024), 0, stream, fit, perm_i, fit_s, out + K_ * F_ + K_ * K_);
  hipLaunchKernelGGL(xnew_k, dim3((K_ * F_ / 4 + TB - 1) / TB), dim3(TB), 0, stream, bufB, perm_i, fit_s, out);

  // sparse S triplets -> A_new
  hipLaunchKernelGGL(trip_sel_k, dim3(1), dim3(TB), 0, stream, perm_i, cptr, csrc, sc, den, ti, tk, tv, tcnt, ctrl);
  hipLaunchKernelGGL(prefix_k, dim3(1), dim3(1024), 0, stream, tcnt, tptr, N_);
  hipLaunchKernelGGL(trip_scatter_k, dim3(TCAP / TB), dim3(TB), 0, stream, ti, tptr, tcur, tidx, ctrl);
  hipLaunchKernelGGL(anew_k, dim3(gM), dim3(TB), 0, stream, ei, tptr, tidx, tk, tv, out + K_ * F_);
  hipLaunchKernelGGL(adiag_k, dim3(1), dim3(TB), 0, stream, out + K_ * F_);

  (void)in_sizes; (void)n_in; (void)out_size; (void)ws_size;
}